// Round 10
// baseline (288.076 us; speedup 1.0000x reference)
//
#include <hip/hip_runtime.h>

#define DCH 1024
#define MSLOT 64
#define NTOK 16384

typedef __bf16 bf16x8 __attribute__((ext_vector_type(8)));
typedef float f32x4 __attribute__((ext_vector_type(4)));
typedef unsigned short u16x8 __attribute__((ext_vector_type(8)));
typedef unsigned short u16x4 __attribute__((ext_vector_type(4)));

__device__ __forceinline__ unsigned short f2bf(float f) {
  unsigned u = __float_as_uint(f);
  u += 0x7fffu + ((u >> 16) & 1u);
  return (unsigned short)(u >> 16);
}
__device__ __forceinline__ float bf2f(unsigned short s) {
  return __uint_as_float(((unsigned)s) << 16);
}

__device__ __forceinline__ void gld16(const void* g, void* l) {
  __builtin_amdgcn_global_load_lds((const __attribute__((address_space(1))) void*)g,
                                   (__attribute__((address_space(3))) void*)l, 16, 0, 0);
}

// ---------------------------------------------------------------------------
// prep_a: weight prep only.
//   b == 0             : sc[m] = bq . memory[m]
//   b in [1,257)       : Wf2 transpose -> Wf2T[c][d] (fp32), 64x64 LDS tiles
//   b in [257,321)     : Wf1 -> bf16
// ---------------------------------------------------------------------------
__global__ __launch_bounds__(256) void prep_a_kernel(
    const float* __restrict__ Wf, float* __restrict__ Wf2T,
    unsigned short* __restrict__ Wf1b,
    const float* __restrict__ bq, const float* __restrict__ memv,
    float* __restrict__ sc) {
  __shared__ float tile[64][65];
  __shared__ float red[256];
  const int b = blockIdx.x, tid = threadIdx.x;

  if (b >= 257) {
    const int j = b - 257;   // Wf1 -> bf16, 64 blocks, 4096 float4 each
#pragma unroll
    for (int i = 0; i < 16; ++i) {
      int f4 = j * 4096 + i * 256 + tid;
      int row = f4 >> 8, c4 = (f4 & 255) * 4;
      float4 v = *(const float4*)(Wf + (size_t)row * 2048 + c4);
      u16x4 o = {f2bf(v.x), f2bf(v.y), f2bf(v.z), f2bf(v.w)};
      *(u16x4*)(Wf1b + row * 1024 + c4) = o;
    }
  } else if (b >= 1) {
    // transpose Wf2: Wf2T[c][d] = Wf[d][1024+c]
    const int t = b - 1;
    const int c0 = (t & 15) * 64, d0 = (t >> 4) * 64;
    const int lane = tid & 63, wv = tid >> 6;
#pragma unroll
    for (int i = 0; i < 16; ++i) {
      int r = wv + i * 4;   // row within tile
      tile[r][lane] = Wf[(size_t)(d0 + r) * 2048 + 1024 + c0 + lane];
    }
    __syncthreads();
#pragma unroll
    for (int i = 0; i < 16; ++i) {
      int r = wv + i * 4;
      Wf2T[(size_t)(c0 + r) * 1024 + d0 + lane] = tile[lane][r];
    }
  } else {
    // sc[m] = sum_e bq[e] * memory[m][e]
    int m = tid >> 2, q = tid & 3;
    float s = 0.f;
    for (int e = q * 256; e < q * 256 + 256; ++e) s += bq[e] * memv[m * 1024 + e];
    red[tid] = s;
    __syncthreads();
    if (tid < 64) sc[tid] = red[tid * 4] + red[tid * 4 + 1] + red[tid * 4 + 2] + red[tid * 4 + 3];
  }
}

// ---------------------------------------------------------------------------
// prep_b: split-K partial GEMMs (M=64, N=1024, K=1024, fp32 VALU).
// ---------------------------------------------------------------------------
__global__ __launch_bounds__(256) void prep_b_kernel(
    const float* __restrict__ memv, const float* __restrict__ Wq,
    const float* __restrict__ Wf2T,
    float* __restrict__ partWm, float* __restrict__ partP) {
  int b = blockIdx.x;
  const int tid = threadIdx.x;
  const int which = b >> 7;
  b &= 127;
  const int kc = b & 7, dt = (b >> 3) & 3, mg = b >> 5;
  const float* B = which ? Wf2T : Wq;
  float* outp = which ? partP : partWm;
  const int d = dt * 256 + tid;
  const int e0 = kc * 128;
  const int m0 = mg * 16;

  float acc[16];
#pragma unroll
  for (int m = 0; m < 16; ++m) acc[m] = 0.f;

  const float* bp = B + (size_t)e0 * 1024 + d;
  const float* mp = memv + m0 * 1024 + e0;
#pragma unroll 4
  for (int e = 0; e < 128; ++e) {
    float wv = bp[(size_t)e * 1024];
#pragma unroll
    for (int m = 0; m < 16; ++m) acc[m] += mp[m * 1024 + e] * wv;
  }
  float* op = outp + ((size_t)kc * 64 + m0) * 1024 + d;
#pragma unroll
  for (int m = 0; m < 16; ++m) op[m * 1024] = acc[m];
}

// ---------------------------------------------------------------------------
// prep_c: reduce 8 partials. idx < 65536 -> Wmb (bf16); else -> P (fp32)
// ---------------------------------------------------------------------------
__global__ __launch_bounds__(256) void prep_c_kernel(
    const float* __restrict__ partWm, const float* __restrict__ partP,
    unsigned short* __restrict__ Wmb, float* __restrict__ P) {
  int idx = blockIdx.x * 256 + threadIdx.x;
  if (idx < 65536) {
    float s = 0.f;
#pragma unroll
    for (int k = 0; k < 8; ++k) s += partWm[k * 65536 + idx];
    Wmb[idx] = f2bf(s);
  } else {
    idx -= 65536;
    float s = 0.f;
#pragma unroll
    for (int k = 0; k < 8; ++k) s += partP[k * 65536 + idx];
    P[idx] = s;
  }
}

// ---------------------------------------------------------------------------
// gemm_h (+ fused sim/top-3): hb = bf16(x) @ Wf1b^T, and for blocks with
// dt<4, additionally sim[tok][dt*16..dt*16+16] = bf16(x) @ Wmb^T + sc using
// the SAME staged A fragments (x read exactly once per tile -> the separate
// sim kernel and its 64 MB x re-read are deleted).  Per-token top-3 of the
// 16-m group is computed in registers via a 4-step quad-butterfly shuffle
// merge and written to psimtop[tok][dt] as {v0,v1,v2, packed idx}.
// ln_relu merges the 4 group-top-3s (superset of global top-3).
// A reg-staged from x f32 (lc=cc^(row&7) source swizzle -> LDS image
// identical to the gld16 layout).  B paths global_load_lds.
// LDS 50KB, launch_bounds(256,2) -> 2 blocks/CU.
// grid 512: tok-tile = b & 63, dt = b >> 6.
// ---------------------------------------------------------------------------
__global__ __launch_bounds__(256, 2) void gemm_h_kernel(
    const float* __restrict__ x, const unsigned short* __restrict__ Wf1b,
    const unsigned short* __restrict__ Wmb, const float* __restrict__ sc,
    unsigned short* __restrict__ hb, float4* __restrict__ psimtop) {
  __shared__ __attribute__((aligned(16))) unsigned short As[256 * 64];
  __shared__ __attribute__((aligned(16))) unsigned short Bs[128 * 64];
  __shared__ __attribute__((aligned(16))) unsigned short Bs2[16 * 64];
  const int tid = threadIdx.x;
  const int wave = tid >> 6, lane = tid & 63;
  const int b = blockIdx.x;
  const int tok0 = (b & 63) * 256, dt = b >> 6, d0 = dt * 128;
  const int quad = lane >> 4, cl = lane & 15;
  const int wm = wave * 64;   // each wave owns 64 token rows, all 128 d cols
  const int sw = ((lane & 7) ^ (lane >> 3)) * 8;    // B staging swizzle (shorts)
  const int cx0 = ((quad) ^ (cl & 7)) * 8;
  const int cx1 = ((quad + 4) ^ (cl & 7)) * 8;
  const bool do_sim = (dt < 4);

  // A staging geometry: thread's 8 chunks are ch = (wave*8+i)*64+lane.
  const int acc_ = lane & 7, ar3 = lane >> 3;
  const int alc = acc_ ^ ar3;          // logical k-chunk (row&7 == lane>>3)

  f32x4 acc[4][8];
#pragma unroll
  for (int i = 0; i < 4; ++i)
#pragma unroll
    for (int j = 0; j < 8; ++j) acc[i][j] = {0.f, 0.f, 0.f, 0.f};
  f32x4 sacc[4];
#pragma unroll
  for (int i = 0; i < 4; ++i) sacc[i] = {0.f, 0.f, 0.f, 0.f};

  for (int kt = 0; kt < 16; ++kt) {
    __syncthreads();
    // A: 256 rows x 64 cols staged from x f32 -> bf16, 8 chunks/thread
#pragma unroll
    for (int i = 0; i < 8; ++i) {
      int row = (wave * 8 + i) * 8 + ar3;
      const size_t goff = (size_t)(tok0 + row) * 1024 + kt * 64 + alc * 8;
      float4 v0 = *(const float4*)(x + goff);
      float4 v1 = *(const float4*)(x + goff + 4);
      u16x8 o = {f2bf(v0.x), f2bf(v0.y), f2bf(v0.z), f2bf(v0.w),
                 f2bf(v1.x), f2bf(v1.y), f2bf(v1.z), f2bf(v1.w)};
      *(u16x8*)(As + ((wave * 8 + i) * 64 + lane) * 8) = o;
    }
#pragma unroll
    for (int i = 0; i < 4; ++i) {   // B: 128 rows x 64 cols = 1024 chunks
      int ch = (wave * 4 + i) * 64 + lane;
      int row = ch >> 3;
      gld16(Wf1b + (size_t)(d0 + row) * 1024 + kt * 64 + sw, Bs + ch * 8);
    }
    if (do_sim && wave < 2) {       // B2: Wmb m-tile, 16 rows x 8 chunks
      int ch = wave * 64 + lane;
      int row = ch >> 3;            // row&7 == lane>>3, matches sw swizzle
      gld16(Wmb + (size_t)(dt * 16 + row) * 1024 + kt * 64 + sw, Bs2 + ch * 8);
    }
    __syncthreads();
#pragma unroll
    for (int ks = 0; ks < 2; ++ks) {
      const int cx = ks ? cx1 : cx0;
      bf16x8 a[4], bb[8];
#pragma unroll
      for (int t = 0; t < 4; ++t)
        a[t] = *(const bf16x8*)(As + (wm + cl + t * 16) * 64 + cx);
#pragma unroll
      for (int t = 0; t < 8; ++t)
        bb[t] = *(const bf16x8*)(Bs + (cl + t * 16) * 64 + cx);
#pragma unroll
      for (int mt = 0; mt < 4; ++mt)
#pragma unroll
        for (int nt = 0; nt < 8; ++nt)
          acc[mt][nt] = __builtin_amdgcn_mfma_f32_16x16x32_bf16(a[mt], bb[nt], acc[mt][nt], 0, 0, 0);
      if (do_sim) {
        bf16x8 b2 = *(const bf16x8*)(Bs2 + cl * 64 + cx);
#pragma unroll
        for (int mt = 0; mt < 4; ++mt)
          sacc[mt] = __builtin_amdgcn_mfma_f32_16x16x32_bf16(a[mt], b2, sacc[mt], 0, 0, 0);
      }
    }
  }

  // epilogue 1: hb store (bias + retrieval handled in ln_relu)
#pragma unroll
  for (int mt = 0; mt < 4; ++mt) {
#pragma unroll
    for (int r = 0; r < 4; ++r) {
      int row = tok0 + wm + mt * 16 + quad * 4 + r;
#pragma unroll
      for (int nt = 0; nt < 8; ++nt) {
        int d = d0 + nt * 16 + cl;
        hb[(size_t)row * 1024 + d] = f2bf(acc[mt][nt][r]);
      }
    }
  }

  // epilogue 2 (dt<4): per-token top-3 of this 16-m group via quad butterfly.
  // Lane holds sim(token = wm+mt*16+quad*4+r, m = dt*16+cl) in sacc[mt][r].
  if (do_sim) {
    const float scv = sc[dt * 16 + cl];
#pragma unroll
    for (int mt = 0; mt < 4; ++mt) {
#pragma unroll
      for (int r = 0; r < 4; ++r) {
        float v0 = sacc[mt][r] + scv;
        int j0 = dt * 16 + cl;
        float v1 = -1e30f, v2 = -1e30f;
        int j1 = 0, j2 = 0;
#pragma unroll
        for (int off = 1; off < 16; off <<= 1) {
          float w0 = __shfl_xor(v0, off), w1 = __shfl_xor(v1, off), w2 = __shfl_xor(v2, off);
          int k0 = __shfl_xor(j0, off), k1 = __shfl_xor(j1, off), k2 = __shfl_xor(j2, off);
          // merge sorted (w0>=w1>=w2) into (v0>=v1>=v2)
          if (w0 > v0) { v2 = v1; j2 = j1; v1 = v0; j1 = j0; v0 = w0; j0 = k0; }
          else if (w0 > v1) { v2 = v1; j2 = j1; v1 = w0; j1 = k0; }
          else if (w0 > v2) { v2 = w0; j2 = k0; }
          if (w1 > v1) { v2 = v1; j2 = j1; v1 = w1; j1 = k1; }
          else if (w1 > v2) { v2 = w1; j2 = k1; }
          if (w2 > v2) { v2 = w2; j2 = k2; }
        }
        if (cl == 0) {
          int tok = tok0 + wm + mt * 16 + quad * 4 + r;
          psimtop[(size_t)tok * 4 + dt] =
              make_float4(v0, v1, v2, __int_as_float(j0 | (j1 << 8) | (j2 << 16)));
        }
      }
    }
  }
}

// ---------------------------------------------------------------------------
// ln_relu: merge 4 group-top-3s -> global top-3 + softmax, then
//          h = hb + bf + w0*P[i0] + w1*P[i1] + w2*P[i2];
//          out = ReLU(LN(h) * gamma + beta).  One wave per token.
// Interleaved lane layout: lane's j-th float4 is at element (j*64+lane)*4.
// grid: 4096 blocks x 256
// ---------------------------------------------------------------------------
__global__ __launch_bounds__(256) void ln_relu_kernel(
    const unsigned short* __restrict__ hb, const float* __restrict__ P,
    const float4* __restrict__ psimtop, const float* __restrict__ bfv,
    const float* __restrict__ gamma, const float* __restrict__ beta,
    float* __restrict__ out) {
  const int tid = threadIdx.x;
  const int wave = tid >> 6, lane = tid & 63;
  const int t = blockIdx.x * 4 + wave;

  // merge 12 candidates (4 groups x sorted top-3) -> global top-3 + softmax.
  float v0 = -1e30f, v1 = -1e30f, v2 = -1e30f;
  int i0 = 0, i1 = 0, i2 = 0;
#pragma unroll
  for (int g = 0; g < 4; ++g) {
    float4 gv = psimtop[(size_t)t * 4 + g];
    int pkk = __float_as_int(gv.w);
    float w0 = gv.x, w1 = gv.y, w2 = gv.z;
    int k0 = pkk & 255, k1 = (pkk >> 8) & 255, k2 = (pkk >> 16) & 255;
    if (w0 > v0) { v2 = v1; i2 = i1; v1 = v0; i1 = i0; v0 = w0; i0 = k0; }
    else if (w0 > v1) { v2 = v1; i2 = i1; v1 = w0; i1 = k0; }
    else if (w0 > v2) { v2 = w0; i2 = k0; }
    if (w1 > v1) { v2 = v1; i2 = i1; v1 = w1; i1 = k1; }
    else if (w1 > v2) { v2 = w1; i2 = k1; }
    if (w2 > v2) { v2 = w2; i2 = k2; }
  }
  float e1 = __expf(v1 - v0), e2 = __expf(v2 - v0);
  float inv = 1.f / (1.f + e1 + e2);
  const float wgt0 = inv, wgt1 = e1 * inv, wgt2 = e2 * inv;

  const float* P0 = P + i0 * 1024;
  const float* P1 = P + i1 * 1024;
  const float* P2 = P + i2 * 1024;
  const unsigned short* hp = hb + (size_t)t * 1024;

  // gather everything into registers first (all loads independent & coalesced)
  u16x4 hv[4];
  float4 b4[4], p0[4], p1[4], p2[4];
#pragma unroll
  for (int j = 0; j < 4; ++j) {
    const int off = (j * 64 + lane) * 4;
    hv[j] = *(const u16x4*)(hp + off);
    b4[j] = *(const float4*)(bfv + off);
    p0[j] = *(const float4*)(P0 + off);
    p1[j] = *(const float4*)(P1 + off);
    p2[j] = *(const float4*)(P2 + off);
  }

  float f[16];
#pragma unroll
  for (int j = 0; j < 4; ++j) {
    f[j * 4 + 0] = bf2f(hv[j][0]) + b4[j].x + wgt0 * p0[j].x + wgt1 * p1[j].x + wgt2 * p2[j].x;
    f[j * 4 + 1] = bf2f(hv[j][1]) + b4[j].y + wgt0 * p0[j].y + wgt1 * p1[j].y + wgt2 * p2[j].y;
    f[j * 4 + 2] = bf2f(hv[j][2]) + b4[j].z + wgt0 * p0[j].z + wgt1 * p1[j].z + wgt2 * p2[j].z;
    f[j * 4 + 3] = bf2f(hv[j][3]) + b4[j].w + wgt0 * p0[j].w + wgt1 * p1[j].w + wgt2 * p2[j].w;
  }
  float s = 0.f, q = 0.f;
#pragma unroll
  for (int j = 0; j < 16; ++j) { s += f[j]; q += f[j] * f[j]; }
#pragma unroll
  for (int off = 32; off; off >>= 1) {
    s += __shfl_xor(s, off);
    q += __shfl_xor(q, off);
  }
  float mean = s * (1.f / 1024.f);
  float var = q * (1.f / 1024.f) - mean * mean;
  float rs = rsqrtf(var + 1e-5f);
  float* op = out + (size_t)t * 1024;
#pragma unroll
  for (int j = 0; j < 4; ++j) {
    const int off = (j * 64 + lane) * 4;
    float4 g4 = *(const float4*)(gamma + off);
    float4 e4 = *(const float4*)(beta + off);
    float4 v;
    v.x = fmaxf((f[j * 4 + 0] - mean) * rs * g4.x + e4.x, 0.f);
    v.y = fmaxf((f[j * 4 + 1] - mean) * rs * g4.y + e4.y, 0.f);
    v.z = fmaxf((f[j * 4 + 2] - mean) * rs * g4.z + e4.z, 0.f);
    v.w = fmaxf((f[j * 4 + 3] - mean) * rs * g4.w + e4.w, 0.f);
    *(float4*)(op + off) = v;
  }
}

// ---------------------------------------------------------------------------
extern "C" void kernel_launch(void* const* d_in, const int* in_sizes, int n_in,
                              void* d_out, int out_size, void* d_ws, size_t ws_size,
                              hipStream_t stream) {
  const float* x     = (const float*)d_in[0];
  const float* memv  = (const float*)d_in[1];
  const float* Wq    = (const float*)d_in[2];
  const float* bq    = (const float*)d_in[3];
  const float* Wf    = (const float*)d_in[4];
  const float* bfv   = (const float*)d_in[5];
  const float* gamma = (const float*)d_in[6];
  const float* beta  = (const float*)d_in[7];
  float* out = (float*)d_out;
  char* ws = (char*)d_ws;

  unsigned short* Wf1b   = (unsigned short*)(ws);              // 2 MB
  unsigned short* Wmb    = (unsigned short*)(ws + 2097152);    // 128 KB
  float*          P      = (float*)(ws + 2228224);             // 256 KB
  float*          sc     = (float*)(ws + 2490368);             // 256 B
  float*          Wf2T   = (float*)(ws + 2752768);             // 4 MB
  float*          partWm = (float*)(ws + 6947072);             // 2 MB
  float*          partP  = (float*)(ws + 9044224);             // 2 MB
  unsigned short* hb     = (unsigned short*)(ws + 11141376);   // 32 MB
  float4*         psimtop= (float4*)(ws + 44695808);           // 1 MB
  // total ws usage: 45,744,128 bytes (< validated 78,250,240)

  hipLaunchKernelGGL(prep_a_kernel, dim3(321), dim3(256), 0, stream,
                     Wf, Wf2T, Wf1b, bq, memv, sc);
  hipLaunchKernelGGL(prep_b_kernel, dim3(256), dim3(256), 0, stream,
                     memv, Wq, Wf2T, partWm, partP);
  hipLaunchKernelGGL(prep_c_kernel, dim3(512), dim3(256), 0, stream,
                     partWm, partP, Wmb, P);
  hipLaunchKernelGGL(gemm_h_kernel, dim3(512), dim3(256), 0, stream,
                     x, Wf1b, Wmb, sc, hb, psimtop);
  hipLaunchKernelGGL(ln_relu_kernel, dim3(4096), dim3(256), 0, stream,
                     hb, P, psimtop, bfv, gamma, beta, out);
}

// Round 11
// 233.824 us; speedup vs baseline: 1.2320x; 1.2320x over previous
//
#include <hip/hip_runtime.h>

#define DCH 1024
#define MSLOT 64
#define NTOK 16384

typedef __bf16 bf16x8 __attribute__((ext_vector_type(8)));
typedef float f32x4 __attribute__((ext_vector_type(4)));
typedef unsigned short u16x8 __attribute__((ext_vector_type(8)));
typedef unsigned short u16x4 __attribute__((ext_vector_type(4)));

__device__ __forceinline__ unsigned short f2bf(float f) {
  unsigned u = __float_as_uint(f);
  u += 0x7fffu + ((u >> 16) & 1u);
  return (unsigned short)(u >> 16);
}
__device__ __forceinline__ float bf2f(unsigned short s) {
  return __uint_as_float(((unsigned)s) << 16);
}

__device__ __forceinline__ void gld16(const void* g, void* l) {
  __builtin_amdgcn_global_load_lds((const __attribute__((address_space(1))) void*)g,
                                   (__attribute__((address_space(3))) void*)l, 16, 0, 0);
}

// ---------------------------------------------------------------------------
// prep_a: weight prep only (x-conversion lives in prep_b where it overlaps
// the split-K GEMM blocks and runs with zero LDS).
//   b == 0             : sc[m] = bq . memory[m]
//   b in [1,257)       : Wf2 transpose -> Wf2T[c][d] (fp32), 64x64 LDS tiles
//   b in [257,321)     : Wf1 -> bf16
// ---------------------------------------------------------------------------
__global__ __launch_bounds__(256) void prep_a_kernel(
    const float* __restrict__ Wf, float* __restrict__ Wf2T,
    unsigned short* __restrict__ Wf1b,
    const float* __restrict__ bq, const float* __restrict__ memv,
    float* __restrict__ sc) {
  __shared__ float tile[64][65];
  __shared__ float red[256];
  const int b = blockIdx.x, tid = threadIdx.x;

  if (b >= 257) {
    const int j = b - 257;   // Wf1 -> bf16, 64 blocks, 4096 float4 each
#pragma unroll
    for (int i = 0; i < 16; ++i) {
      int f4 = j * 4096 + i * 256 + tid;
      int row = f4 >> 8, c4 = (f4 & 255) * 4;
      float4 v = *(const float4*)(Wf + (size_t)row * 2048 + c4);
      u16x4 o = {f2bf(v.x), f2bf(v.y), f2bf(v.z), f2bf(v.w)};
      *(u16x4*)(Wf1b + row * 1024 + c4) = o;
    }
  } else if (b >= 1) {
    // transpose Wf2: Wf2T[c][d] = Wf[d][1024+c]
    const int t = b - 1;
    const int c0 = (t & 15) * 64, d0 = (t >> 4) * 64;
    const int lane = tid & 63, wv = tid >> 6;
#pragma unroll
    for (int i = 0; i < 16; ++i) {
      int r = wv + i * 4;   // row within tile
      tile[r][lane] = Wf[(size_t)(d0 + r) * 2048 + 1024 + c0 + lane];
    }
    __syncthreads();
#pragma unroll
    for (int i = 0; i < 16; ++i) {
      int r = wv + i * 4;
      Wf2T[(size_t)(c0 + r) * 1024 + d0 + lane] = tile[lane][r];
    }
  } else {
    // sc[m] = sum_e bq[e] * memory[m][e]
    int m = tid >> 2, q = tid & 3;
    float s = 0.f;
    for (int e = q * 256; e < q * 256 + 256; ++e) s += bq[e] * memv[m * 1024 + e];
    red[tid] = s;
    __syncthreads();
    if (tid < 64) sc[tid] = red[tid * 4] + red[tid * 4 + 1] + red[tid * 4 + 2] + red[tid * 4 + 3];
  }
}

// ---------------------------------------------------------------------------
// prep_b: split-K partial GEMMs (M=64, N=1024, K=1024, fp32 VALU) in blocks
// [0,256), PLUS x (f32) -> xb (bf16) streaming conversion in blocks
// [256,2304).  The GEMM blocks occupy ~1 block/CU; the LDS-free conversion
// blocks fill the rest of the machine and overlap the GEMM instead of
// running as a separate serial phase.
//   x-conversion: 8 float4 per thread, all loads issued before converts.
// ---------------------------------------------------------------------------
__global__ __launch_bounds__(256) void prep_b_kernel(
    const float* __restrict__ memv, const float* __restrict__ Wq,
    const float* __restrict__ Wf2T,
    float* __restrict__ partWm, float* __restrict__ partP,
    const float* __restrict__ x, unsigned short* __restrict__ xb) {
  int b = blockIdx.x;
  const int tid = threadIdx.x;

  if (b >= 256) {
    // x -> bf16: 2048 blocks, each thread handles 8 float4 (32 floats),
    // strided by 256 threads so every load/store instruction is contiguous.
    const int xblk = b - 256;
    const float* xp = x + ((size_t)xblk * 2048 + tid) * 4;
    unsigned short* op = xb + ((size_t)xblk * 2048 + tid) * 4;
    float4 a[8];
#pragma unroll
    for (int i = 0; i < 8; ++i) a[i] = *(const float4*)(xp + (size_t)i * 1024);
#pragma unroll
    for (int i = 0; i < 8; ++i) {
      u16x4 o = {f2bf(a[i].x), f2bf(a[i].y), f2bf(a[i].z), f2bf(a[i].w)};
      *(u16x4*)(op + (size_t)i * 1024) = o;
    }
    return;
  }

  const int which = b >> 7;
  b &= 127;
  const int kc = b & 7, dt = (b >> 3) & 3, mg = b >> 5;
  const float* B = which ? Wf2T : Wq;
  float* outp = which ? partP : partWm;
  const int d = dt * 256 + tid;
  const int e0 = kc * 128;
  const int m0 = mg * 16;

  float acc[16];
#pragma unroll
  for (int m = 0; m < 16; ++m) acc[m] = 0.f;

  const float* bp = B + (size_t)e0 * 1024 + d;
  const float* mp = memv + m0 * 1024 + e0;
#pragma unroll 4
  for (int e = 0; e < 128; ++e) {
    float wv = bp[(size_t)e * 1024];
#pragma unroll
    for (int m = 0; m < 16; ++m) acc[m] += mp[m * 1024 + e] * wv;
  }
  float* op = outp + ((size_t)kc * 64 + m0) * 1024 + d;
#pragma unroll
  for (int m = 0; m < 16; ++m) op[m * 1024] = acc[m];
}

// ---------------------------------------------------------------------------
// prep_c: reduce 8 partials. idx < 65536 -> Wmb (bf16); else -> P (fp32)
// ---------------------------------------------------------------------------
__global__ __launch_bounds__(256) void prep_c_kernel(
    const float* __restrict__ partWm, const float* __restrict__ partP,
    unsigned short* __restrict__ Wmb, float* __restrict__ P) {
  int idx = blockIdx.x * 256 + threadIdx.x;
  if (idx < 65536) {
    float s = 0.f;
#pragma unroll
    for (int k = 0; k < 8; ++k) s += partWm[k * 65536 + idx];
    Wmb[idx] = f2bf(s);
  } else {
    idx -= 65536;
    float s = 0.f;
#pragma unroll
    for (int k = 0; k < 8; ++k) s += partP[k * 65536 + idx];
    P[idx] = s;
  }
}

// ---------------------------------------------------------------------------
// sim_topk: sim = xb @ Wmb^T + sc  (64 tok x 64 m per block), then per-token
// top-3 + softmax -> meta.  XOR-swizzled LDS (see gemm_h comment).
// grid: 256 blocks x 256
// ---------------------------------------------------------------------------
__global__ __launch_bounds__(256) void sim_topk_kernel(
    const unsigned short* __restrict__ xb, const unsigned short* __restrict__ Wmb,
    const float* __restrict__ sc, float4* __restrict__ meta) {
  __shared__ __attribute__((aligned(16))) unsigned short As[64 * 64];
  __shared__ __attribute__((aligned(16))) unsigned short Bs[64 * 64];
  __shared__ float sim_s[64 * 65];
  const int tid = threadIdx.x;
  const int wave = tid >> 6, lane = tid & 63;
  const int tok0 = blockIdx.x * 64;
  const int quad = lane >> 4, cl = lane & 15;
  const int sw = ((lane & 7) ^ (lane >> 3)) * 8;    // staging swizzle (shorts)
  const int cx0 = ((quad) ^ (cl & 7)) * 8;          // read swizzle ks=0
  const int cx1 = ((quad + 4) ^ (cl & 7)) * 8;      // read swizzle ks=1

  f32x4 acc[4];
#pragma unroll
  for (int j = 0; j < 4; ++j) acc[j] = {0.f, 0.f, 0.f, 0.f};

  for (int kt = 0; kt < 16; ++kt) {
    __syncthreads();
#pragma unroll
    for (int i = 0; i < 2; ++i) {
      int ch = (wave * 2 + i) * 64 + lane;
      int row = ch >> 3;
      gld16(xb + (size_t)(tok0 + row) * 1024 + kt * 64 + sw, As + ch * 8);
      gld16(Wmb + row * 1024 + kt * 64 + sw, Bs + ch * 8);
    }
    __syncthreads();
#pragma unroll
    for (int ks = 0; ks < 2; ++ks) {
      const int cx = ks ? cx1 : cx0;
      bf16x8 a = *(const bf16x8*)(As + (wave * 16 + cl) * 64 + cx);
#pragma unroll
      for (int nt = 0; nt < 4; ++nt) {
        bf16x8 bb = *(const bf16x8*)(Bs + (cl + nt * 16) * 64 + cx);
        acc[nt] = __builtin_amdgcn_mfma_f32_16x16x32_bf16(a, bb, acc[nt], 0, 0, 0);
      }
    }
  }
#pragma unroll
  for (int nt = 0; nt < 4; ++nt)
#pragma unroll
    for (int r = 0; r < 4; ++r) {
      int lt = wave * 16 + quad * 4 + r;
      int mc = nt * 16 + cl;
      sim_s[lt * 65 + mc] = acc[nt][r] + sc[mc];
    }
  __syncthreads();
  if (tid < 64) {
    const float* sp = sim_s + tid * 65;
    float s0 = -1e30f, s1 = -1e30f, s2 = -1e30f;
    int i0 = 0, i1 = 0, i2 = 0;
    for (int m = 0; m < 64; ++m) {
      float v = sp[m];
      if (v > s0) { s2 = s1; i2 = i1; s1 = s0; i1 = i0; s0 = v; i0 = m; }
      else if (v > s1) { s2 = s1; i2 = i1; s1 = v; i1 = m; }
      else if (v > s2) { s2 = v; i2 = m; }
    }
    float e1 = __expf(s1 - s0), e2 = __expf(s2 - s0);
    float inv = 1.f / (1.f + e1 + e2);
    meta[tok0 + tid] = make_float4(inv, e1 * inv, e2 * inv,
                                   __int_as_float(i0 | (i1 << 8) | (i2 << 16)));
  }
}

// ---------------------------------------------------------------------------
// gemm_h: hb = xb @ Wf1b^T  (bf16)
// 256(tok) x 128(d) tile, BK=64, XOR-swizzled LDS layout:
//   row stride 64 shorts = 128 B = 32 banks, so un-swizzled fragment reads
//   put all 16 cl-lanes of a quad on the same 4 banks (16-way conflict).
//   Since global_load_lds writes at wave-uniform-base + lane*16, swizzle the
//   GLOBAL source column instead: LDS chunk (row, lane&7) holds logical
//   K-chunk (lane&7)^(lane>>3 & 7); reads use physical chunk
//   (quad+4ks)^(cl&7)  -> 2 lanes/bank-group = free.
// grid 512 linear, XCD swizzle: tok-tile = b & 63, dt = b >> 6.
// ---------------------------------------------------------------------------
__global__ __launch_bounds__(256, 2) void gemm_h_kernel(
    const unsigned short* __restrict__ xb, const unsigned short* __restrict__ Wf1b,
    unsigned short* __restrict__ hb) {
  __shared__ __attribute__((aligned(16))) unsigned short As[256 * 64];
  __shared__ __attribute__((aligned(16))) unsigned short Bs[128 * 64];
  const int tid = threadIdx.x;
  const int wave = tid >> 6, lane = tid & 63;
  const int b = blockIdx.x;
  const int tok0 = (b & 63) * 256, d0 = (b >> 6) * 128;
  const int quad = lane >> 4, cl = lane & 15;
  const int wm = wave * 64;   // each wave owns 64 token rows, all 128 d cols
  const int sw = ((lane & 7) ^ (lane >> 3)) * 8;    // staging swizzle (shorts)
  const int cx0 = ((quad) ^ (cl & 7)) * 8;
  const int cx1 = ((quad + 4) ^ (cl & 7)) * 8;

  f32x4 acc[4][8];
#pragma unroll
  for (int i = 0; i < 4; ++i)
#pragma unroll
    for (int j = 0; j < 8; ++j) acc[i][j] = {0.f, 0.f, 0.f, 0.f};

  for (int kt = 0; kt < 16; ++kt) {
    __syncthreads();
#pragma unroll
    for (int i = 0; i < 8; ++i) {   // A: 256 rows x 64 cols = 2048 chunks
      int ch = (wave * 8 + i) * 64 + lane;
      int row = ch >> 3;
      gld16(xb + (size_t)(tok0 + row) * 1024 + kt * 64 + sw, As + ch * 8);
    }
#pragma unroll
    for (int i = 0; i < 4; ++i) {   // B: 128 rows x 64 cols = 1024 chunks
      int ch = (wave * 4 + i) * 64 + lane;
      int row = ch >> 3;
      gld16(Wf1b + (size_t)(d0 + row) * 1024 + kt * 64 + sw, Bs + ch * 8);
    }
    __syncthreads();
#pragma unroll
    for (int ks = 0; ks < 2; ++ks) {
      const int cx = ks ? cx1 : cx0;
      bf16x8 a[4], bb[8];
#pragma unroll
      for (int t = 0; t < 4; ++t)
        a[t] = *(const bf16x8*)(As + (wm + cl + t * 16) * 64 + cx);
#pragma unroll
      for (int t = 0; t < 8; ++t)
        bb[t] = *(const bf16x8*)(Bs + (cl + t * 16) * 64 + cx);
#pragma unroll
      for (int mt = 0; mt < 4; ++mt)
#pragma unroll
        for (int nt = 0; nt < 8; ++nt)
          acc[mt][nt] = __builtin_amdgcn_mfma_f32_16x16x32_bf16(a[mt], bb[nt], acc[mt][nt], 0, 0, 0);
    }
  }

  // epilogue: plain bf16 store (bias + retrieval handled in ln_relu)
#pragma unroll
  for (int mt = 0; mt < 4; ++mt) {
#pragma unroll
    for (int r = 0; r < 4; ++r) {
      int row = tok0 + wm + mt * 16 + quad * 4 + r;
#pragma unroll
      for (int nt = 0; nt < 8; ++nt) {
        int d = d0 + nt * 16 + cl;
        hb[(size_t)row * 1024 + d] = f2bf(acc[mt][nt][r]);
      }
    }
  }
}

// ---------------------------------------------------------------------------
// ln_relu: h = hb + bf + w0*P[i0] + w1*P[i1] + w2*P[i2];
//          out = ReLU(LN(h) * gamma + beta).  One wave per token.
// Interleaved lane layout: lane's j-th float4 is at element (j*64+lane)*4,
// so every global load/store instruction is wave-contiguous (full cache
// lines, full-line stores).
// grid: 4096 blocks x 256
// ---------------------------------------------------------------------------
__global__ __launch_bounds__(256) void ln_relu_kernel(
    const unsigned short* __restrict__ hb, const float* __restrict__ P,
    const float4* __restrict__ meta, const float* __restrict__ bfv,
    const float* __restrict__ gamma, const float* __restrict__ beta,
    float* __restrict__ out) {
  const int tid = threadIdx.x;
  const int wave = tid >> 6, lane = tid & 63;
  const int t = blockIdx.x * 4 + wave;

  float4 mv = meta[t];
  int pk = __float_as_int(mv.w);
  const float* P0 = P + (pk & 255) * 1024;
  const float* P1 = P + ((pk >> 8) & 255) * 1024;
  const float* P2 = P + ((pk >> 16) & 255) * 1024;

  const unsigned short* hp = hb + (size_t)t * 1024;

  // gather everything into registers first (all loads independent & coalesced)
  u16x4 hv[4];
  float4 b4[4], p0[4], p1[4], p2[4];
#pragma unroll
  for (int j = 0; j < 4; ++j) {
    const int off = (j * 64 + lane) * 4;
    hv[j] = *(const u16x4*)(hp + off);
    b4[j] = *(const float4*)(bfv + off);
    p0[j] = *(const float4*)(P0 + off);
    p1[j] = *(const float4*)(P1 + off);
    p2[j] = *(const float4*)(P2 + off);
  }

  float f[16];
#pragma unroll
  for (int j = 0; j < 4; ++j) {
    f[j * 4 + 0] = bf2f(hv[j][0]) + b4[j].x + mv.x * p0[j].x + mv.y * p1[j].x + mv.z * p2[j].x;
    f[j * 4 + 1] = bf2f(hv[j][1]) + b4[j].y + mv.x * p0[j].y + mv.y * p1[j].y + mv.z * p2[j].y;
    f[j * 4 + 2] = bf2f(hv[j][2]) + b4[j].z + mv.x * p0[j].z + mv.y * p1[j].z + mv.z * p2[j].z;
    f[j * 4 + 3] = bf2f(hv[j][3]) + b4[j].w + mv.x * p0[j].w + mv.y * p1[j].w + mv.z * p2[j].w;
  }
  float s = 0.f, q = 0.f;
#pragma unroll
  for (int j = 0; j < 16; ++j) { s += f[j]; q += f[j] * f[j]; }
#pragma unroll
  for (int off = 32; off; off >>= 1) {
    s += __shfl_xor(s, off);
    q += __shfl_xor(q, off);
  }
  float mean = s * (1.f / 1024.f);
  float var = q * (1.f / 1024.f) - mean * mean;
  float rs = rsqrtf(var + 1e-5f);
  float* op = out + (size_t)t * 1024;
#pragma unroll
  for (int j = 0; j < 4; ++j) {
    const int off = (j * 64 + lane) * 4;
    float4 g4 = *(const float4*)(gamma + off);
    float4 e4 = *(const float4*)(beta + off);
    float4 v;
    v.x = fmaxf((f[j * 4 + 0] - mean) * rs * g4.x + e4.x, 0.f);
    v.y = fmaxf((f[j * 4 + 1] - mean) * rs * g4.y + e4.y, 0.f);
    v.z = fmaxf((f[j * 4 + 2] - mean) * rs * g4.z + e4.z, 0.f);
    v.w = fmaxf((f[j * 4 + 3] - mean) * rs * g4.w + e4.w, 0.f);
    *(float4*)(op + off) = v;
  }
}

// ---------------------------------------------------------------------------
extern "C" void kernel_launch(void* const* d_in, const int* in_sizes, int n_in,
                              void* d_out, int out_size, void* d_ws, size_t ws_size,
                              hipStream_t stream) {
  const float* x     = (const float*)d_in[0];
  const float* memv  = (const float*)d_in[1];
  const float* Wq    = (const float*)d_in[2];
  const float* bq    = (const float*)d_in[3];
  const float* Wf    = (const float*)d_in[4];
  const float* bfv   = (const float*)d_in[5];
  const float* gamma = (const float*)d_in[6];
  const float* beta  = (const float*)d_in[7];
  float* out = (float*)d_out;
  char* ws = (char*)d_ws;

  unsigned short* Wf1b   = (unsigned short*)(ws);              // 2 MB
  unsigned short* Wmb    = (unsigned short*)(ws + 2097152);    // 128 KB
  float*          P      = (float*)(ws + 2228224);             // 256 KB
  float*          sc     = (float*)(ws + 2490368);             // 256 B
  float4*         meta   = (float4*)(ws + 2490624);            // 256 KB
  float*          Wf2T   = (float*)(ws + 2752768);             // 4 MB
  float*          partWm = (float*)(ws + 6947072);             // 2 MB
  float*          partP  = (float*)(ws + 9044224);             // 2 MB
  unsigned short* xb     = (unsigned short*)(ws + 11141376);   // 32 MB
  unsigned short* hb     = (unsigned short*)(ws + 44695808);   // 32 MB
  // total ws usage: 78,250,240 bytes

  hipLaunchKernelGGL(prep_a_kernel, dim3(321), dim3(256), 0, stream,
                     Wf, Wf2T, Wf1b, bq, memv, sc);
  hipLaunchKernelGGL(prep_b_kernel, dim3(2304), dim3(256), 0, stream,
                     memv, Wq, Wf2T, partWm, partP, x, xb);
  hipLaunchKernelGGL(prep_c_kernel, dim3(512), dim3(256), 0, stream,
                     partWm, partP, Wmb, P);
  hipLaunchKernelGGL(sim_topk_kernel, dim3(256), dim3(256), 0, stream,
                     xb, Wmb, sc, meta);
  hipLaunchKernelGGL(gemm_h_kernel, dim3(512), dim3(256), 0, stream,
                     xb, Wf1b, hb);
  hipLaunchKernelGGL(ln_relu_kernel, dim3(4096), dim3(256), 0, stream,
                     hb, P, meta, bfv, gamma, beta, out);
}